// Round 5
// baseline (215.030 us; speedup 1.0000x reference)
//
#include <hip/hip_runtime.h>
#include <hip/hip_fp16.h>
#include <math.h>

// Problem constants (B=8, S=2048, T=128)
#define S_LEN 2048
#define T_DIM 128
#define BM 128               // tokens per block (m-range)
#define NBLK 256             // (mb 0..127) x (ph 0..1)
#define P_ELEMS (16384u * 128u)  // one ph-half partial plane, f16 elements
#define RSTRIDE 132          // f32 stride of LDS reduction plane (2-way max alias)

typedef _Float16 half8 __attribute__((ext_vector_type(8)));
typedef _Float16 half4 __attribute__((ext_vector_type(4)));
typedef float floatx16 __attribute__((ext_vector_type(16)));

// ---------------------------------------------------------------------------
// Kernel 0: W fp32 [t][p][q] -> W16f fp16 in MFMA-B-fragment order:
//   W16f[ ((p*4 + tc)*8 + kc)*512 + lh2*256 + (t&31)*8 + j ]
//     tc=t>>5, kc=q>>4, lh2=(q>>3)&1, j=q&7
// ---------------------------------------------------------------------------
__global__ __launch_bounds__(256) void convert_w_kernel(
    const float* __restrict__ W, _Float16* __restrict__ W16f) {
  const int t = blockIdx.x >> 1;
  const int qh = blockIdx.x & 1;
  const int tid = threadIdx.x;
  const int tc = t >> 5;
  const int tl = t & 31;
#pragma unroll
  for (int it = 0; it < 4; ++it) {
    const int e8 = it * 256 + tid;        // 0..1023 half8-chunks over [p][q-half]
    const int p = e8 >> 3;
    const int q = qh * 64 + (e8 & 7) * 8;
    const float* src = W + (size_t)t * 16384 + (size_t)p * 128 + q;
    const float4 v0 = *(const float4*)src;
    const float4 v1 = *(const float4*)(src + 4);
    half8 h;
    h[0] = (_Float16)v0.x; h[1] = (_Float16)v0.y;
    h[2] = (_Float16)v0.z; h[3] = (_Float16)v0.w;
    h[4] = (_Float16)v1.x; h[5] = (_Float16)v1.y;
    h[6] = (_Float16)v1.z; h[7] = (_Float16)v1.w;
    const int kc = q >> 4;
    const int lh2 = (q >> 3) & 1;
    *(half8*)(W16f + ((size_t)((p * 4 + tc) * 8 + kc)) * 512 + lh2 * 256 + tl * 8) = h;
  }
}

// ---------------------------------------------------------------------------
// Kernel 1: out[b,i,t] = sum(w_red)*tanh(b_comp[t]) + b_red  (baseline row)
// ---------------------------------------------------------------------------
__global__ __launch_bounds__(256) void init_out_kernel(
    const float* __restrict__ w_red, const float* __restrict__ b_comp,
    const float* __restrict__ b_red, float* __restrict__ out) {
  __shared__ float red4[4];
  const int tid = threadIdx.x;
  float part = 0.f;
#pragma unroll
  for (int i = 0; i < 8; ++i) part += w_red[tid * 8 + i];
#pragma unroll
  for (int off = 32; off > 0; off >>= 1) part += __shfl_down(part, off, 64);
  if ((tid & 63) == 0) red4[tid >> 6] = part;
  __syncthreads();
  const float Sw = red4[0] + red4[1] + red4[2] + red4[3];
  const float br = b_red[0];
  const size_t base = (size_t)blockIdx.x * 1024 + (size_t)tid * 4;
  const int t0 = (int)(base & 127);
  float4 v;
  v.x = Sw * tanhf(b_comp[t0 + 0]) + br;
  v.y = Sw * tanhf(b_comp[t0 + 1]) + br;
  v.z = Sw * tanhf(b_comp[t0 + 2]) + br;
  v.w = Sw * tanhf(b_comp[t0 + 3]) + br;
  *(float4*)(out + base) = v;
}

// ---------------------------------------------------------------------------
// Kernel 2: MFMA main kernel. Block = (mb = blk>>1, ph = blk&1).
// ph == XCD parity (XCD = blk%8) -> each XCD's blocks read the SAME contiguous
// 2MB half of W16f => L2-resident. 8 waves = (th x2, kh x4); each wave covers
// all 4 m-tiles -> zero B-fragment redundancy; barrier-free p-loop.
// FIX vs round 4: the 4 kh waves hold q-chunk PARTIALS of the same (m,t)
// tiles -> must be reduced in-block (serial 4-phase LDS reduction) before the
// f16 P-plane store. Round 4 plain-stored them to the same addresses (race).
// v_mfma_f32_32x32x16_f16: A lane m=l&31, k=(l>>5)*8+j; B n=l&31 same k;
// C/D col=l&31, row=(r&3)+8*(r>>2)+4*(l>>5)   [m74/m101-verified]
// ---------------------------------------------------------------------------
__global__ __launch_bounds__(512, 2) void main_kernel(
    const float* __restrict__ tok, const _Float16* __restrict__ W16f,
    _Float16* __restrict__ P) {
  __shared__ _Float16 tokT2[64 * 128];   // 16 KB: [p_local][ (m&31)*4 + (m>>5) ]
  __shared__ float red[128 * RSTRIDE];   // 66 KB: kh-reduction plane [m][t]

  const int tid = threadIdx.x;
  const int lane = tid & 63;
  const int wave = tid >> 6;  // 0..7
  const int th = wave & 1;    // t-half (64 cols)
  const int kh = wave >> 1;   // q-quarter (32 of 128)
  const int l31 = lane & 31;
  const int lh = lane >> 5;
  const int blk = blockIdx.x;
  const int ph = blk & 1;     // p-half, == XCD parity
  const int mb = blk >> 1;    // 0..127
  const size_t tokbase = (size_t)mb * BM * T_DIM;

  // ---- stage tokT2: tok[m, ph*64 + p] as f16, mh-packed for ds_read_b64 ----
#pragma unroll
  for (int it = 0; it < 4; ++it) {
    const int f = it * 512 + tid;   // 0..2047 over [m(128)][p4(16)]
    const int m = f >> 4;
    const int p0 = (f & 15) * 4;
    const float4 v = *(const float4*)(tok + tokbase + (size_t)m * 128 + ph * 64 + p0);
    const int mi = (m & 31) * 4 + (m >> 5);
    tokT2[(p0 + 0) * 128 + mi] = (_Float16)v.x;
    tokT2[(p0 + 1) * 128 + mi] = (_Float16)v.y;
    tokT2[(p0 + 2) * 128 + mi] = (_Float16)v.z;
    tokT2[(p0 + 3) * 128 + mi] = (_Float16)v.w;
  }

  // ---- per-lane h fragments: h16[mh][ks], q0 = kh*32 + ks*16 + lh*8 ----
  half8 h16[4][2];
#pragma unroll
  for (int mh = 0; mh < 4; ++mh) {
    const int m = mh * 32 + l31;
#pragma unroll
    for (int ks = 0; ks < 2; ++ks) {
      const int q0 = kh * 32 + ks * 16 + lh * 8;
      const float4 v0 = *(const float4*)(tok + tokbase + (size_t)m * 128 + q0);
      const float4 v1 = *(const float4*)(tok + tokbase + (size_t)m * 128 + q0 + 4);
      h16[mh][ks][0] = (_Float16)tanhf(v0.x);
      h16[mh][ks][1] = (_Float16)tanhf(v0.y);
      h16[mh][ks][2] = (_Float16)tanhf(v0.z);
      h16[mh][ks][3] = (_Float16)tanhf(v0.w);
      h16[mh][ks][4] = (_Float16)tanhf(v1.x);
      h16[mh][ks][5] = (_Float16)tanhf(v1.y);
      h16[mh][ks][6] = (_Float16)tanhf(v1.z);
      h16[mh][ks][7] = (_Float16)tanhf(v1.w);
    }
  }
  __syncthreads();  // tokT2 ready

  // Fragment offsets within a p-slice (f16 elems)
  int off[2][2];
#pragma unroll
  for (int tt = 0; tt < 2; ++tt)
#pragma unroll
    for (int ks = 0; ks < 2; ++ks)
      off[tt][ks] = (((th * 2 + tt) * 8 + kh * 2 + ks) << 9) + lane * 8;

  floatx16 acc[4][2];  // [mh][tt]
#pragma unroll
  for (int mh = 0; mh < 4; ++mh)
#pragma unroll
    for (int tt = 0; tt < 2; ++tt)
#pragma unroll
      for (int r = 0; r < 16; ++r) acc[mh][tt][r] = 0.f;

  half8 bf0[2][2], bf1[2][2];
  const _Float16* Wbase = W16f + (size_t)ph * 64 * 16384;

  auto loadB = [&](half8 (&bf)[2][2], int p) {
    const _Float16* wp = Wbase + (size_t)p * 16384;
#pragma unroll
    for (int tt = 0; tt < 2; ++tt)
#pragma unroll
      for (int ks = 0; ks < 2; ++ks)
        bf[tt][ks] = *(const half8*)(wp + off[tt][ks]);
  };

  auto compute = [&](half8 (&bf)[2][2], int p) {
    const half4 tk = *(const half4*)(tokT2 + p * 128 + l31 * 4);
#pragma unroll
    for (int ks = 0; ks < 2; ++ks) {
      half8 a0 = h16[0][ks] * tk[0];
      half8 a1 = h16[1][ks] * tk[1];
      half8 a2 = h16[2][ks] * tk[2];
      half8 a3 = h16[3][ks] * tk[3];
      acc[0][0] = __builtin_amdgcn_mfma_f32_32x32x16_f16(a0, bf[0][ks], acc[0][0], 0, 0, 0);
      acc[0][1] = __builtin_amdgcn_mfma_f32_32x32x16_f16(a0, bf[1][ks], acc[0][1], 0, 0, 0);
      acc[1][0] = __builtin_amdgcn_mfma_f32_32x32x16_f16(a1, bf[0][ks], acc[1][0], 0, 0, 0);
      acc[1][1] = __builtin_amdgcn_mfma_f32_32x32x16_f16(a1, bf[1][ks], acc[1][1], 0, 0, 0);
      acc[2][0] = __builtin_amdgcn_mfma_f32_32x32x16_f16(a2, bf[0][ks], acc[2][0], 0, 0, 0);
      acc[2][1] = __builtin_amdgcn_mfma_f32_32x32x16_f16(a2, bf[1][ks], acc[2][1], 0, 0, 0);
      acc[3][0] = __builtin_amdgcn_mfma_f32_32x32x16_f16(a3, bf[0][ks], acc[3][0], 0, 0, 0);
      acc[3][1] = __builtin_amdgcn_mfma_f32_32x32x16_f16(a3, bf[1][ks], acc[3][1], 0, 0, 0);
    }
  };

  // Software pipeline over the block's 64-p half, no barriers:
  loadB(bf0, 0);
  for (int p = 0; p < 64; p += 2) {
    loadB(bf1, p + 1);
    compute(bf0, p);
    if (p + 2 < 64) loadB(bf0, p + 2);
    compute(bf1, p + 1);
  }

  // ---- serial 4-phase kh reduction in LDS (wave-uniform branches) ----
  __syncthreads();
#pragma unroll
  for (int phase = 0; phase < 4; ++phase) {
    if (kh == phase) {
#pragma unroll
      for (int mh = 0; mh < 4; ++mh)
#pragma unroll
        for (int tt = 0; tt < 2; ++tt) {
          const int tcol = (th * 2 + tt) * 32 + l31;
#pragma unroll
          for (int r = 0; r < 16; ++r) {
            const int m_loc = (r & 3) + 8 * (r >> 2) + 4 * lh;
            const int addr = (mh * 32 + m_loc) * RSTRIDE + tcol;
            if (phase == 0) red[addr] = acc[mh][tt][r];
            else            red[addr] += acc[mh][tt][r];
          }
        }
    }
    __syncthreads();
  }

  // ---- cooperative f16 store of the block's P plane (coalesced half8) ----
  _Float16* Pp = P + (size_t)ph * P_ELEMS;
#pragma unroll
  for (int it = 0; it < 4; ++it) {
    const int chunk = it * 512 + tid;  // 0..2047 over [m(128)][t-chunk(16)]
    const int m = chunk >> 4;
    const int t0 = (chunk & 15) * 8;
    half8 h;
#pragma unroll
    for (int j = 0; j < 8; ++j) h[j] = (_Float16)red[m * RSTRIDE + t0 + j];
    *(half8*)(Pp + (size_t)(mb * BM + m) * 128 + t0) = h;
  }
}

// ---------------------------------------------------------------------------
// Kernel 3: epilogue. v = P0[m,t]+P1[m,t]; act=tanh(v+bc);
// out[b, heads[m], t] += w_red[s]*(act - tanh(bc)).
// ---------------------------------------------------------------------------
__global__ __launch_bounds__(256) void epilogue_kernel(
    const _Float16* __restrict__ P, const int* __restrict__ heads,
    const float* __restrict__ b_comp, const float* __restrict__ w_red,
    float* __restrict__ out) {
  const int gid = blockIdx.x * 256 + threadIdx.x;  // 0..262143
  const int m = gid >> 4;
  const int t0 = (gid & 15) * 8;
  const half8 p0 = *(const half8*)(P + (size_t)m * 128 + t0);
  const half8 p1 = *(const half8*)(P + P_ELEMS + (size_t)m * 128 + t0);
  const int b = m >> 11;
  const int s = m & 2047;
  const int head = heads[m];
  const float wr = w_red[s];
  float* orow = out + ((size_t)b * S_LEN + head) * T_DIM;
#pragma unroll
  for (int j = 0; j < 8; ++j) {
    const float bc = b_comp[t0 + j];
    const float v = (float)p0[j] + (float)p1[j] + bc;
    atomicAdd(orow + t0 + j, wr * (tanhf(v) - tanhf(bc)));
  }
}

// ---------------------------------------------------------------------------
extern "C" void kernel_launch(void* const* d_in, const int* in_sizes, int n_in,
                              void* d_out, int out_size, void* d_ws, size_t ws_size,
                              hipStream_t stream) {
  const float* tok    = (const float*)d_in[0];
  // d_in[1] = dep_embeddings: dead input (source bug), unused
  const int*   heads  = (const int*)d_in[2];
  const float* W      = (const float*)d_in[3];
  const float* b_comp = (const float*)d_in[4];
  const float* w_red  = (const float*)d_in[5];
  const float* b_red  = (const float*)d_in[6];
  float* out = (float*)d_out;

  _Float16* W16f = (_Float16*)d_ws;              // 4 MB, fragment-ordered
  _Float16* P    = (_Float16*)d_ws + 2097152;    // 2 x 4 MB f16 partial planes

  convert_w_kernel<<<256, 256, 0, stream>>>(W, W16f);
  init_out_kernel<<<2048, 256, 0, stream>>>(w_red, b_comp, b_red, out);
  main_kernel<<<NBLK, 512, 0, stream>>>(tok, W16f, P);
  epilogue_kernel<<<1024, 256, 0, stream>>>(P, heads, b_comp, w_red, out);
}